// Round 15
// baseline (171.671 us; speedup 1.0000x reference)
//
#include <hip/hip_runtime.h>
#include <stdint.h>

typedef float f32x4 __attribute__((ext_vector_type(4)));
typedef short bf16x8 __attribute__((ext_vector_type(8)));
typedef float fragc __attribute__((ext_vector_type(4)));
typedef uint32_t u32x4 __attribute__((ext_vector_type(4)));

__device__ __forceinline__ uint32_t pk2(float lo, float hi) {
  // (bf16(lo) | bf16(hi)<<16) via one v_perm_b32 (truncating)
  return __builtin_amdgcn_perm(__float_as_uint(hi), __float_as_uint(lo), 0x07060302u);
}

__device__ __forceinline__ void gload16(const void* g, void* l) {
  __builtin_amdgcn_global_load_lds((const __attribute__((address_space(1))) uint32_t*)g,
                                   (__attribute__((address_space(3))) uint32_t*)l, 16, 0, 0);
}

#define WS_B_OFF 67108864ull  // B'' at ws + 64 MiB

// ---------- Pass 1 (unchanged, ~86% of mixed-stream floor): [1024 s][512 r][64 h] f32
//   -> bf16 ws[kq 128][rw 8][h 64][r 64][16B]
__global__ __launch_bounds__(512) void pack_kernel(const float* __restrict__ Ag,
                                                   const float* __restrict__ Bg,
                                                   uint8_t* __restrict__ ws) {
  const int bid  = blockIdx.x;
  const int rw   = bid & 7;
  const int kq   = (bid >> 3) & 127;
  const int side = bid >> 10;
  const int t    = threadIdx.x;

  const f32x4* S4 = (const f32x4*)(side ? Bg : Ag);
  uint8_t* dst = ws + (side ? WS_B_OFF : 0ull);

  const int base = rw * 1024 + t;
  f32x4 r1[8], r2[8];
#pragma unroll
  for (int e = 0; e < 8; ++e)
    r1[e] = __builtin_nontemporal_load(&S4[(size_t)(kq * 8 + e) * 8192 + base]);
#pragma unroll
  for (int e = 0; e < 8; ++e)
    r2[e] = __builtin_nontemporal_load(&S4[(size_t)(kq * 8 + e) * 8192 + base + 512]);

  const int hq = t & 15;
  const int ra = t >> 4;  // 0..31
#pragma unroll
  for (int e = 0; e < 4; ++e) {  // window-1 stores need only r1 (start at vmcnt(8))
    const int h = hq * 4 + e;
    u32x4 o1;
    o1[0] = pk2(r1[0][e], r1[1][e]); o1[1] = pk2(r1[2][e], r1[3][e]);
    o1[2] = pk2(r1[4][e], r1[5][e]); o1[3] = pk2(r1[6][e], r1[7][e]);
    uint8_t* plane = dst + ((size_t)((kq * 8 + rw) * 64 + h)) * 1024;
    *(u32x4*)(plane + ra * 16) = o1;
  }
#pragma unroll
  for (int e = 0; e < 4; ++e) {
    const int h = hq * 4 + e;
    u32x4 o2;
    o2[0] = pk2(r2[0][e], r2[1][e]); o2[1] = pk2(r2[2][e], r2[3][e]);
    o2[2] = pk2(r2[4][e], r2[5][e]); o2[3] = pk2(r2[6][e], r2[7][e]);
    uint8_t* plane = dst + ((size_t)((kq * 8 + rw) * 64 + h)) * 1024;
    *(u32x4*)(plane + (ra + 32) * 16) = o2;
  }
}

// ---------- Pass 2: C[i,j,h] = (1/1024) sum_s A''*B''
// tile 256i x 256j x 1h -> logical staged volume halves to 256MB (gemm has tracked
// volume/~9.5TB/s across R6/R10/R12/R13/R14 — VMEM-service-bound, not barrier-bound).
// 512 thr, 8 waves = (wi 2) x (wj 4); per wave 128i x 64j: 32 MFMA + 12 ds_read_b128
// per kt (same fat ratio as the best R10 structure). BK=32, dbuf 2 x 32KB.
// acc = 128 f32/lane -> launch_bounds(512,2) (256-VGPR budget; R11 spill trap).
// XCD map x = (h>>4)*2 + tj: all 16 h-writers of each 64B C-line co-XCD (L2 merge,
// proven pattern), B re-reads XCD-local, A-dup pair served by L3 (R13-proven).
// K-loop: counted vmcnt(4) + raw barriers (R14).
__global__ __launch_bounds__(512, 2) void gemm_kernel(const uint8_t* __restrict__ ws,
                                                      float* __restrict__ Og) {
  __shared__ alignas(16) uint8_t lds[65536];  // 2 x (A 16KB + B 16KB)

  const int bid = blockIdx.x;
  const int x   = bid & 7;
  const int r   = bid >> 3;              // 0..31
  const int h   = (x >> 1) * 16 + (r & 15);  // 0..63
  const int tj  = x & 1;
  const int ti  = r >> 4;
  const int i0  = ti * 256;
  const int j0  = tj * 256;

  const int t = threadIdx.x, lane = t & 63, w = t >> 6;
  const int wi = w >> 2, wj = w & 3;     // wave = 128i-half x 64j-quarter
  const int frl = lane & 15, frg = lane >> 4;

  const uint8_t* Apk = ws;
  const uint8_t* Bpk = ws + WS_B_OFF;

  fragc acc[8][4];
#pragma unroll
  for (int m = 0; m < 8; ++m)
#pragma unroll
    for (int n = 0; n < 4; ++n)
      acc[m][n] = (fragc)0.0f;

  // staging: 32 planes (16 A + 16 B) of 1KB; wave w stages side=w>>2, ko=w&3,
  // p = u (rw-offset). ws plane byte: ((kq*8 + rw)*64 + h)*1024.
  const int s_side = w >> 2;             // 0 = A-waves, 1 = B-waves
  const int s_ko   = w & 3;
  const uint8_t* s_base = (s_side ? Bpk : Apk);
  const int s_rw0 = (s_side ? (j0 >> 6) : (i0 >> 6));

#define ISSUE(kt, b)                                                              \
  {                                                                               \
    _Pragma("unroll") for (int u = 0; u < 4; ++u) {                               \
      const size_t pl = ((size_t)(((kt) * 4 + s_ko) * 8 + s_rw0 + u) * 64 + h);   \
      gload16(s_base + pl * 1024 + lane * 16,                                     \
              lds + (b) * 32768 + (w * 4 + u) * 1024 + lane * 16);                \
    }                                                                             \
  }

  ISSUE(0, 0)

  for (int kt = 0; kt < 32; ++kt) {
    const int b = kt & 1;
    if (kt < 31) {
      ISSUE(kt + 1, b ^ 1)  // 4 gloads/thread for next tile, kept in flight
      asm volatile("s_waitcnt vmcnt(4)" ::: "memory");  // own tile-kt loads done
    } else {
      asm volatile("s_waitcnt vmcnt(0)" ::: "memory");
    }
    __builtin_amdgcn_s_barrier();        // all waves' tile-kt loads done
    asm volatile("" ::: "memory");
    {
      const uint8_t* La = lds + b * 32768;          // [ko 4][p 4][1KB]
      const uint8_t* Lb = La + 16384;
      bf16x8 fb[4];
#pragma unroll
      for (int n = 0; n < 4; ++n)
        fb[n] = *(const bf16x8*)(Lb + (frg * 4 + wj) * 1024 + (n * 16 + frl) * 16);
#pragma unroll
      for (int m = 0; m < 8; ++m) {
        bf16x8 fa = *(const bf16x8*)(La + (frg * 4 + wi * 2 + (m >> 2)) * 1024 +
                                     ((m & 3) * 16 + frl) * 16);
#pragma unroll
        for (int n = 0; n < 4; ++n)
          acc[m][n] = __builtin_amdgcn_mfma_f32_16x16x32_bf16(fa, fb[n], acc[m][n], 0, 0, 0);
      }
    }
    asm volatile("" ::: "memory");
    __builtin_amdgcn_s_barrier();        // buf b free for ISSUE(kt+2) next iter
  }
#undef ISSUE

  // epilogue: direct 4B cached stores; the 16 h-sibling blocks of each 64B C-line
  // are co-XCD + co-resident -> L2 assembles full lines (cached stores only; NT
  // would bypass merge — R7 lesson).
  const float scale = 1.0f / 1024.0f;
#pragma unroll
  for (int m = 0; m < 8; ++m) {
#pragma unroll
    for (int q = 0; q < 4; ++q) {
      const int ig = i0 + wi * 128 + m * 16 + frg * 4 + q;
#pragma unroll
      for (int n = 0; n < 4; ++n) {
        const int jg = j0 + wj * 64 + n * 16 + frl;
        Og[((size_t)ig * 512 + jg) * 64 + h] = acc[m][n][q] * scale;
      }
    }
  }
}

extern "C" void kernel_launch(void* const* d_in, const int* in_sizes, int n_in,
                              void* d_out, int out_size, void* d_ws, size_t ws_size,
                              hipStream_t stream) {
  const float* a = (const float*)d_in[0];
  const float* b = (const float*)d_in[1];
  float* out = (float*)d_out;
  uint8_t* ws = (uint8_t*)d_ws;
  pack_kernel<<<2048, 512, 0, stream>>>(a, b, ws);
  gemm_kernel<<<256, 512, 0, stream>>>(ws, out);
}